// Round 7
// baseline (300.789 us; speedup 1.0000x reference)
//
#include <hip/hip_runtime.h>

// MHA: B=8, N=1024, D=768, H=12, HD=64. FLOAT32 in/out, bf16 MFMA internally.
// Phase 0: weight prep (transpose W{q,k,v} per head, cast Wo) f32 -> bf16 ws
// Phase 1: QKV projection; Q pre-scaled by 768^-0.5*log2(e); V TRANSPOSED
// Phase 2: flash attention: split-KV x2 (wave pairs, exact combine), KV tile
//          width 64 (1 LDS round-trip per 32 MFMAs), XCD-swizzled block ids,
//          no barriers in KV loop (ping-pong wave-private P)
// Phase 3: output projection, M=16/wave, 24 waves/CU

typedef __attribute__((ext_vector_type(8))) short short8;   // 8 x bf16 bits
typedef __attribute__((ext_vector_type(4))) float floatx4;  // MFMA acc

#define MFMA16(a, b, c) __builtin_amdgcn_mfma_f32_16x16x32_bf16((a), (b), (c), 0, 0, 0)

#if __has_builtin(__builtin_amdgcn_exp2f)
#define EXP2(x) __builtin_amdgcn_exp2f(x)
#else
#define EXP2(x) __expf(0.6931471805599453f * (x))
#endif
#if __has_builtin(__builtin_amdgcn_rcpf)
#define RCP(x) __builtin_amdgcn_rcpf(x)
#else
#define RCP(x) (1.0f / (x))
#endif

__device__ __forceinline__ unsigned short f2bf(float f) {
    union { float f; unsigned int i; } c;
    c.f = f;
    unsigned int i = c.i;
    return (unsigned short)((i + 0x7fffu + ((i >> 16) & 1u)) >> 16);  // RNE
}
__device__ __forceinline__ unsigned short f2bf_trunc(float f) {
    union { float f; unsigned int i; } c;
    c.f = f;
    return (unsigned short)(c.i >> 16);  // folds into ds_write_b16_d16_hi
}

// ---------------------------------------------------------------------------
// Phase 0: Wt[h][e][k] = W[h][k][e] (bf16), Wo_bf = bf16(Wo).
// ---------------------------------------------------------------------------
__global__ __launch_bounds__(256) void prep_weights(
    const float* __restrict__ Wq, const float* __restrict__ Wk,
    const float* __restrict__ Wv, const float* __restrict__ Wo,
    unsigned short* __restrict__ Wqt, unsigned short* __restrict__ Wkt,
    unsigned short* __restrict__ Wvt, unsigned short* __restrict__ Wob)
{
    int tid = blockIdx.x * 256 + threadIdx.x;  // 0..147455
    if (tid < 49152) {                          // 12 heads * 4096 only
        int h = tid >> 12, r = tid & 4095;
        int e = r >> 6, k = r & 63;
        int src = h * 4096 + k * 64 + e, dst = h * 4096 + e * 64 + k;
        Wqt[dst] = f2bf(Wq[src]);
        Wkt[dst] = f2bf(Wk[src]);
        Wvt[dst] = f2bf(Wv[src]);
    }
    for (int i = tid; i < 589824; i += 147456) Wob[i] = f2bf(Wo[i]);
}

// ---------------------------------------------------------------------------
// Phase 1: Q/K (row-major, Q pre-scaled by 768^-0.5*log2e) and Vt per head.
// grid (N/64, B*H), block 256 (4 waves, 16 seq rows each). float4 x-loads.
// ---------------------------------------------------------------------------
__global__ __launch_bounds__(256) void qkv_proj(
    const float* __restrict__ x,
    const unsigned short* __restrict__ Wqt, const unsigned short* __restrict__ Wkt,
    const unsigned short* __restrict__ Wvt,
    const float* __restrict__ bq, const float* __restrict__ bk,
    const float* __restrict__ bv,
    unsigned short* __restrict__ Q, unsigned short* __restrict__ K,
    unsigned short* __restrict__ Vt)
{
    const int bh = blockIdx.y;
    const int b = bh / 12, h = bh % 12;
    const int wave = threadIdx.x >> 6, lane = threadIdx.x & 63;
    const int lrow = lane & 15, quad = lane >> 4;
    const int row0 = blockIdx.x * 64 + wave * 16;
    const float scale = 0.052058776672f;  // 768^-0.5 * log2(e): p = 2^s

    const float* xrow = x + ((size_t)(b * 1024 + row0 + lrow)) * 768 + h * 64;
    float4 xv0 = *(const float4*)(xrow + quad * 8);
    float4 xv1 = *(const float4*)(xrow + quad * 8 + 4);
    float4 xv2 = *(const float4*)(xrow + 32 + quad * 8);
    float4 xv3 = *(const float4*)(xrow + 32 + quad * 8 + 4);
    short8 a0, a1;
    a0[0] = (short)f2bf(xv0.x); a0[1] = (short)f2bf(xv0.y);
    a0[2] = (short)f2bf(xv0.z); a0[3] = (short)f2bf(xv0.w);
    a0[4] = (short)f2bf(xv1.x); a0[5] = (short)f2bf(xv1.y);
    a0[6] = (short)f2bf(xv1.z); a0[7] = (short)f2bf(xv1.w);
    a1[0] = (short)f2bf(xv2.x); a1[1] = (short)f2bf(xv2.y);
    a1[2] = (short)f2bf(xv2.z); a1[3] = (short)f2bf(xv2.w);
    a1[4] = (short)f2bf(xv3.x); a1[5] = (short)f2bf(xv3.y);
    a1[6] = (short)f2bf(xv3.z); a1[7] = (short)f2bf(xv3.w);

    const floatx4 zero = { 0.f, 0.f, 0.f, 0.f };

    // ---- Q and K ----
    const unsigned short* Wm[2] = { Wqt + h * 4096, Wkt + h * 4096 };
    const float* bm[2] = { bq + h * 64, bk + h * 64 };
    unsigned short* Om[2] = { Q, K };
    #pragma unroll
    for (int m = 0; m < 2; ++m) {
        const unsigned short* W = Wm[m];
        unsigned short* O = Om[m] + ((size_t)bh * 1024 + row0) * 64;
        #pragma unroll
        for (int t = 0; t < 4; ++t) {
            short8 b0 = *(const short8*)(W + (t * 16 + lrow) * 64 + quad * 8);
            short8 b1 = *(const short8*)(W + (t * 16 + lrow) * 64 + 32 + quad * 8);
            floatx4 acc = zero;
            acc = MFMA16(a0, b0, acc);
            acc = MFMA16(a1, b1, acc);
            float bias = bm[m][t * 16 + lrow];
            #pragma unroll
            for (int r = 0; r < 4; ++r) {
                float v = acc[r] + bias;
                if (m == 0) v *= scale;  // fold score scale (incl log2e) into Q
                O[(quad * 4 + r) * 64 + t * 16 + lrow] = f2bf(v);
            }
        }
    }

    // ---- V transposed: D[e][seq] = sum_k Wv[k][e] * x[seq][k] ----
    {
        const unsigned short* W = Wvt + h * 4096;
        const float* bvh = bv + h * 64;
        unsigned short* O = Vt + (size_t)bh * 64 * 1024;
        #pragma unroll
        for (int t = 0; t < 4; ++t) {
            short8 wa0 = *(const short8*)(W + (t * 16 + lrow) * 64 + quad * 8);
            short8 wa1 = *(const short8*)(W + (t * 16 + lrow) * 64 + 32 + quad * 8);
            floatx4 acc = zero;
            acc = MFMA16(wa0, a0, acc);  // B-frag = x fragment
            acc = MFMA16(wa1, a1, acc);
            #pragma unroll
            for (int r = 0; r < 4; ++r) {
                int e = t * 16 + quad * 4 + r;
                O[(size_t)e * 1024 + row0 + lrow] = f2bf(acc[r] + bvh[e]);
            }
        }
    }
}

// ---------------------------------------------------------------------------
// Phase 2: flash attention. grid (16, 96), block 256.
// Block = 64 q-rows of one (b,h). Wave pair (half=0/1) splits KV range:
// wave handles 32 q-rows x 512 kv in 8 iterations of kv-width 64
// (32 MFMAs per LDS round-trip). Exact combine at end (no-max softmax:
// O and sum(p) add linearly). XCD swizzle keeps each bh's K/V on one XCD.
// ---------------------------------------------------------------------------
__global__ __launch_bounds__(256, 4) void attn_kernel(
    const unsigned short* __restrict__ Q, const unsigned short* __restrict__ K,
    const unsigned short* __restrict__ Vt, unsigned short* __restrict__ AO)
{
    // P tile per wave: [buf][mm][row 16][col 72 (64+pad)] -> 36864 B total
    __shared__ __align__(16) unsigned short ldsP[4][2][2][16][72];

    const int id = blockIdx.x + 16 * blockIdx.y;         // flat, x-fastest
    const int bh = (id & 7) * 12 + ((id % 96) >> 3);     // XCD-clustered bh
    const int qb = id / 96;                              // 0..15
    const int b = bh / 12, h = bh % 12;
    const int wave = threadIdx.x >> 6, lane = threadIdx.x & 63;
    const int lrow = lane & 15, quad = lane >> 4;
    const int mg = wave >> 1;          // which 32-row group of the block
    const int half = wave & 1;         // which KV half
    const int qrow0 = qb * 64 + mg * 32;
    const int kv0 = half * 512;

    const unsigned short* Qb = Q + (size_t)bh * 1024 * 64;
    const unsigned short* Kb = K + (size_t)bh * 1024 * 64;
    const unsigned short* Vb = Vt + (size_t)bh * 64 * 1024;

    short8 aq[2][2];
    #pragma unroll
    for (int mm = 0; mm < 2; ++mm) {
        const unsigned short* qr = Qb + (size_t)(qrow0 + mm * 16 + lrow) * 64;
        aq[mm][0] = *(const short8*)(qr + quad * 8);
        aq[mm][1] = *(const short8*)(qr + 32 + quad * 8);
    }

    const floatx4 zero = { 0.f, 0.f, 0.f, 0.f };
    float part[2][4];
    floatx4 Oacc[2][4];
    #pragma unroll
    for (int mm = 0; mm < 2; ++mm) {
        #pragma unroll
        for (int r = 0; r < 4; ++r) part[mm][r] = 0.f;
        #pragma unroll
        for (int t = 0; t < 4; ++t) Oacc[mm][t] = zero;
    }

    for (int jt = 0; jt < 8; ++jt) {
        const int j0 = kv0 + jt * 64;
        const int buf = jt & 1;

        // K fragments: 4 n-tiles x 2 k-frags (contiguous row reads of K)
        short8 kf[4][2];
        #pragma unroll
        for (int g = 0; g < 4; ++g) {
            const unsigned short* kr = Kb + (size_t)(j0 + g * 16 + lrow) * 64;
            kf[g][0] = *(const short8*)(kr + quad * 8);
            kf[g][1] = *(const short8*)(kr + 32 + quad * 8);
        }

        // S = Q K^T for both m-tiles, 4 n-tiles
        floatx4 S[2][4];
        #pragma unroll
        for (int mm = 0; mm < 2; ++mm)
            #pragma unroll
            for (int g = 0; g < 4; ++g) {
                floatx4 s = zero;
                s = MFMA16(aq[mm][0], kf[g][0], s);
                s = MFMA16(aq[mm][1], kf[g][1], s);
                S[mm][g] = s;
            }

        // V fragments issued now, in flight during exp + LDS round-trip
        short8 vf[4][2];
        #pragma unroll
        for (int t = 0; t < 4; ++t) {
            const unsigned short* vr = Vb + (size_t)(t * 16 + lrow) * 1024 + j0;
            vf[t][0] = *(const short8*)(vr + quad * 8);
            vf[t][1] = *(const short8*)(vr + 32 + quad * 8);
        }

        // p = 2^s (log2e folded into Q); write P tile (trunc-to-bf16 stores)
        #pragma unroll
        for (int mm = 0; mm < 2; ++mm)
            #pragma unroll
            for (int g = 0; g < 4; ++g)
                #pragma unroll
                for (int r = 0; r < 4; ++r) {
                    float p = EXP2(S[mm][g][r]);
                    part[mm][r] += p;
                    ldsP[wave][buf][mm][quad * 4 + r][g * 16 + lrow] = f2bf_trunc(p);
                }

        // P: C-layout -> A-layout via wave-private LDS (no barrier needed)
        short8 aP[2][2];
        #pragma unroll
        for (int mm = 0; mm < 2; ++mm) {
            aP[mm][0] = *(const short8*)(&ldsP[wave][buf][mm][lrow][quad * 8]);
            aP[mm][1] = *(const short8*)(&ldsP[wave][buf][mm][lrow][32 + quad * 8]);
        }

        // O += P V
        #pragma unroll
        for (int t = 0; t < 4; ++t)
            #pragma unroll
            for (int mm = 0; mm < 2; ++mm) {
                Oacc[mm][t] = MFMA16(aP[mm][0], vf[t][0], Oacc[mm][t]);
                Oacc[mm][t] = MFMA16(aP[mm][1], vf[t][1], Oacc[mm][t]);
            }
    }

    // ---- combine KV halves (exact: O and sum(p) add linearly) ----
    __syncthreads();
    float* fbuf = (float*)ldsP;
    float* obuf = fbuf;          // [2 mg][32 i][64 lane]
    float* pbuf = fbuf + 4096;   // [2 mg][8 i][64 lane]
    if (half == 1) {
        #pragma unroll
        for (int mm = 0; mm < 2; ++mm) {
            #pragma unroll
            for (int t = 0; t < 4; ++t)
                #pragma unroll
                for (int r = 0; r < 4; ++r)
                    obuf[(mg * 32 + mm * 16 + t * 4 + r) * 64 + lane] = Oacc[mm][t][r];
            #pragma unroll
            for (int r = 0; r < 4; ++r)
                pbuf[(mg * 8 + mm * 4 + r) * 64 + lane] = part[mm][r];
        }
    }
    __syncthreads();
    if (half == 0) {
        #pragma unroll
        for (int mm = 0; mm < 2; ++mm) {
            float inv[4];
            #pragma unroll
            for (int r = 0; r < 4; ++r) {
                float ts = part[mm][r] + pbuf[(mg * 8 + mm * 4 + r) * 64 + lane];
                ts += __shfl_xor(ts, 1);
                ts += __shfl_xor(ts, 2);
                ts += __shfl_xor(ts, 4);
                ts += __shfl_xor(ts, 8);
                inv[r] = RCP(ts);
            }
            #pragma unroll
            for (int t = 0; t < 4; ++t)
                #pragma unroll
                for (int r = 0; r < 4; ++r) {
                    float val = (Oacc[mm][t][r]
                        + obuf[(mg * 32 + mm * 16 + t * 4 + r) * 64 + lane]) * inv[r];
                    size_t idx = ((size_t)(b * 1024 + qrow0 + mm * 16 + quad * 4 + r)) * 768
                               + h * 64 + t * 16 + lrow;
                    AO[idx] = f2bf(val);
                }
        }
    }
}

// ---------------------------------------------------------------------------
// Phase 3: Y = AO @ Wo^T + bo. AO [8192 x 768] bf16, Wob bf16, Y f32.
// grid (12, 128), block 256; wave = 16 rows -> 1536 blocks, 24 waves/CU.
// ---------------------------------------------------------------------------
__global__ __launch_bounds__(256) void out_proj(
    const unsigned short* __restrict__ AO, const unsigned short* __restrict__ Wob,
    const float* __restrict__ bo, float* __restrict__ Y)
{
    const int wave = threadIdx.x >> 6, lane = threadIdx.x & 63;
    const int lrow = lane & 15, quad = lane >> 4;
    const int row0 = blockIdx.y * 64 + wave * 16;
    const int c0 = blockIdx.x * 64;

    const floatx4 zero = { 0.f, 0.f, 0.f, 0.f };
    floatx4 acc[4];
    #pragma unroll
    for (int t = 0; t < 4; ++t) acc[t] = zero;

    #pragma unroll 2
    for (int k0 = 0; k0 < 768; k0 += 32) {
        short8 a = *(const short8*)(AO + (size_t)(row0 + lrow) * 768 + k0 + quad * 8);
        #pragma unroll
        for (int t = 0; t < 4; ++t) {
            short8 bfr = *(const short8*)(Wob + (size_t)(c0 + t * 16 + lrow) * 768
                                          + k0 + quad * 8);
            acc[t] = MFMA16(a, bfr, acc[t]);
        }
    }
    #pragma unroll
    for (int t = 0; t < 4; ++t) {
        float bias = bo[c0 + t * 16 + lrow];
        #pragma unroll
        for (int r = 0; r < 4; ++r) {
            Y[(size_t)(row0 + quad * 4 + r) * 768 + c0 + t * 16 + lrow]
                = acc[t][r] + bias;
        }
    }
}

extern "C" void kernel_launch(void* const* d_in, const int* in_sizes, int n_in,
                              void* d_out, int out_size, void* d_ws, size_t ws_size,
                              hipStream_t stream)
{
    const float* x  = (const float*)d_in[0];
    const float* Wq = (const float*)d_in[1];
    const float* Wk = (const float*)d_in[2];
    const float* Wv = (const float*)d_in[3];
    const float* bq = (const float*)d_in[4];
    const float* bk = (const float*)d_in[5];
    const float* bv = (const float*)d_in[6];
    const float* Wo = (const float*)d_in[7];
    const float* bo = (const float*)d_in[8];

    // ws layout (bf16 elements)
    unsigned short* Q   = (unsigned short*)d_ws;        // 6291456
    unsigned short* K   = Q + 6291456;                  // 6291456
    unsigned short* Vt  = K + 6291456;                  // 6291456 (transposed)
    unsigned short* AO  = Vt + 6291456;                 // 6291456
    unsigned short* Wqt = AO + 6291456;                 // 49152
    unsigned short* Wkt = Wqt + 49152;                  // 49152
    unsigned short* Wvt = Wkt + 49152;                  // 49152
    unsigned short* Wob = Wvt + 49152;                  // 589824
    float* Y = (float*)d_out;

    prep_weights<<<dim3(576), 256, 0, stream>>>(Wq, Wk, Wv, Wo, Wqt, Wkt, Wvt, Wob);
    qkv_proj<<<dim3(16, 96), 256, 0, stream>>>(x, Wqt, Wkt, Wvt, bq, bk, bv, Q, K, Vt);
    attn_kernel<<<dim3(16, 96), 256, 0, stream>>>(Q, K, Vt, AO);
    out_proj<<<dim3(12, 128), 256, 0, stream>>>(AO, Wob, bo, Y);
}

// Round 8
// 255.528 us; speedup vs baseline: 1.1771x; 1.1771x over previous
//
#include <hip/hip_runtime.h>

// MHA: B=8, N=1024, D=768, H=12, HD=64. FLOAT32 in/out, bf16 MFMA internally.
// Phase 0: weight prep (transpose W{q,k,v} per head, cast Wo) f32 -> bf16 ws
// Phase 1: QKV projection; Q pre-scaled by 768^-0.5*log2(e); V TRANSPOSED
// Phase 2: flash attention: split-KV x2 (wave pairs, exact combine), KV tile
//          width 64 (1 LDS round-trip per 32 MFMAs), XCD-swizzled block ids,
//          no barriers in KV loop. NO launch-bounds occupancy force: round 7
//          showed (256,4) clamps to 64 VGPR and spills (~150 live regs here).
// Phase 3: output projection, M=32 rows/wave (M=16 variant measured -28us)

typedef __attribute__((ext_vector_type(8))) short short8;   // 8 x bf16 bits
typedef __attribute__((ext_vector_type(4))) float floatx4;  // MFMA acc

#define MFMA16(a, b, c) __builtin_amdgcn_mfma_f32_16x16x32_bf16((a), (b), (c), 0, 0, 0)

#if __has_builtin(__builtin_amdgcn_exp2f)
#define EXP2(x) __builtin_amdgcn_exp2f(x)
#else
#define EXP2(x) __expf(0.6931471805599453f * (x))
#endif
#if __has_builtin(__builtin_amdgcn_rcpf)
#define RCP(x) __builtin_amdgcn_rcpf(x)
#else
#define RCP(x) (1.0f / (x))
#endif

__device__ __forceinline__ unsigned short f2bf(float f) {
    union { float f; unsigned int i; } c;
    c.f = f;
    unsigned int i = c.i;
    return (unsigned short)((i + 0x7fffu + ((i >> 16) & 1u)) >> 16);  // RNE
}
__device__ __forceinline__ unsigned short f2bf_trunc(float f) {
    union { float f; unsigned int i; } c;
    c.f = f;
    return (unsigned short)(c.i >> 16);  // folds into ds_write_b16_d16_hi
}

// ---------------------------------------------------------------------------
// Phase 0: Wt[h][e][k] = W[h][k][e] (bf16), Wo_bf = bf16(Wo).
// ---------------------------------------------------------------------------
__global__ __launch_bounds__(256) void prep_weights(
    const float* __restrict__ Wq, const float* __restrict__ Wk,
    const float* __restrict__ Wv, const float* __restrict__ Wo,
    unsigned short* __restrict__ Wqt, unsigned short* __restrict__ Wkt,
    unsigned short* __restrict__ Wvt, unsigned short* __restrict__ Wob)
{
    int tid = blockIdx.x * 256 + threadIdx.x;  // 0..147455
    if (tid < 49152) {                          // 12 heads * 4096 only
        int h = tid >> 12, r = tid & 4095;
        int e = r >> 6, k = r & 63;
        int src = h * 4096 + k * 64 + e, dst = h * 4096 + e * 64 + k;
        Wqt[dst] = f2bf(Wq[src]);
        Wkt[dst] = f2bf(Wk[src]);
        Wvt[dst] = f2bf(Wv[src]);
    }
    for (int i = tid; i < 589824; i += 147456) Wob[i] = f2bf(Wo[i]);
}

// ---------------------------------------------------------------------------
// Phase 1: Q/K (row-major, Q pre-scaled by 768^-0.5*log2e) and Vt per head.
// grid (N/64, B*H), block 256 (4 waves, 16 seq rows each). float4 x-loads.
// ---------------------------------------------------------------------------
__global__ __launch_bounds__(256) void qkv_proj(
    const float* __restrict__ x,
    const unsigned short* __restrict__ Wqt, const unsigned short* __restrict__ Wkt,
    const unsigned short* __restrict__ Wvt,
    const float* __restrict__ bq, const float* __restrict__ bk,
    const float* __restrict__ bv,
    unsigned short* __restrict__ Q, unsigned short* __restrict__ K,
    unsigned short* __restrict__ Vt)
{
    const int bh = blockIdx.y;
    const int b = bh / 12, h = bh % 12;
    const int wave = threadIdx.x >> 6, lane = threadIdx.x & 63;
    const int lrow = lane & 15, quad = lane >> 4;
    const int row0 = blockIdx.x * 64 + wave * 16;
    const float scale = 0.052058776672f;  // 768^-0.5 * log2(e): p = 2^s

    const float* xrow = x + ((size_t)(b * 1024 + row0 + lrow)) * 768 + h * 64;
    float4 xv0 = *(const float4*)(xrow + quad * 8);
    float4 xv1 = *(const float4*)(xrow + quad * 8 + 4);
    float4 xv2 = *(const float4*)(xrow + 32 + quad * 8);
    float4 xv3 = *(const float4*)(xrow + 32 + quad * 8 + 4);
    short8 a0, a1;
    a0[0] = (short)f2bf(xv0.x); a0[1] = (short)f2bf(xv0.y);
    a0[2] = (short)f2bf(xv0.z); a0[3] = (short)f2bf(xv0.w);
    a0[4] = (short)f2bf(xv1.x); a0[5] = (short)f2bf(xv1.y);
    a0[6] = (short)f2bf(xv1.z); a0[7] = (short)f2bf(xv1.w);
    a1[0] = (short)f2bf(xv2.x); a1[1] = (short)f2bf(xv2.y);
    a1[2] = (short)f2bf(xv2.z); a1[3] = (short)f2bf(xv2.w);
    a1[4] = (short)f2bf(xv3.x); a1[5] = (short)f2bf(xv3.y);
    a1[6] = (short)f2bf(xv3.z); a1[7] = (short)f2bf(xv3.w);

    const floatx4 zero = { 0.f, 0.f, 0.f, 0.f };

    // ---- Q and K ----
    const unsigned short* Wm[2] = { Wqt + h * 4096, Wkt + h * 4096 };
    const float* bm[2] = { bq + h * 64, bk + h * 64 };
    unsigned short* Om[2] = { Q, K };
    #pragma unroll
    for (int m = 0; m < 2; ++m) {
        const unsigned short* W = Wm[m];
        unsigned short* O = Om[m] + ((size_t)bh * 1024 + row0) * 64;
        #pragma unroll
        for (int t = 0; t < 4; ++t) {
            short8 b0 = *(const short8*)(W + (t * 16 + lrow) * 64 + quad * 8);
            short8 b1 = *(const short8*)(W + (t * 16 + lrow) * 64 + 32 + quad * 8);
            floatx4 acc = zero;
            acc = MFMA16(a0, b0, acc);
            acc = MFMA16(a1, b1, acc);
            float bias = bm[m][t * 16 + lrow];
            #pragma unroll
            for (int r = 0; r < 4; ++r) {
                float v = acc[r] + bias;
                if (m == 0) v *= scale;  // fold score scale (incl log2e) into Q
                O[(quad * 4 + r) * 64 + t * 16 + lrow] = f2bf(v);
            }
        }
    }

    // ---- V transposed: D[e][seq] = sum_k Wv[k][e] * x[seq][k] ----
    {
        const unsigned short* W = Wvt + h * 4096;
        const float* bvh = bv + h * 64;
        unsigned short* O = Vt + (size_t)bh * 64 * 1024;
        #pragma unroll
        for (int t = 0; t < 4; ++t) {
            short8 wa0 = *(const short8*)(W + (t * 16 + lrow) * 64 + quad * 8);
            short8 wa1 = *(const short8*)(W + (t * 16 + lrow) * 64 + 32 + quad * 8);
            floatx4 acc = zero;
            acc = MFMA16(wa0, a0, acc);  // B-frag = x fragment
            acc = MFMA16(wa1, a1, acc);
            #pragma unroll
            for (int r = 0; r < 4; ++r) {
                int e = t * 16 + quad * 4 + r;
                O[(size_t)e * 1024 + row0 + lrow] = f2bf(acc[r] + bvh[e]);
            }
        }
    }
}

// ---------------------------------------------------------------------------
// Phase 2: flash attention. grid (16, 96), block 256.
// Block = 64 q-rows of one (b,h). Wave pair (half=0/1) splits KV range:
// wave handles 32 q-rows x 512 kv in 8 iterations of kv-width 64
// (32 MFMAs per LDS round-trip). Exact combine at end (no-max softmax:
// O and sum(p) add linearly). XCD swizzle keeps each bh's K/V on one XCD.
// ---------------------------------------------------------------------------
__global__ __launch_bounds__(256) void attn_kernel(
    const unsigned short* __restrict__ Q, const unsigned short* __restrict__ K,
    const unsigned short* __restrict__ Vt, unsigned short* __restrict__ AO)
{
    // P tile per wave: [buf][mm][row 16][col 72 (64+pad)] -> 36864 B total
    __shared__ __align__(16) unsigned short ldsP[4][2][2][16][72];

    const int id = blockIdx.x + 16 * blockIdx.y;         // flat, x-fastest
    const int bh = (id & 7) * 12 + ((id % 96) >> 3);     // XCD-clustered bh
    const int qb = id / 96;                              // 0..15
    const int b = bh / 12, h = bh % 12;
    const int wave = threadIdx.x >> 6, lane = threadIdx.x & 63;
    const int lrow = lane & 15, quad = lane >> 4;
    const int mg = wave >> 1;          // which 32-row group of the block
    const int half = wave & 1;         // which KV half
    const int qrow0 = qb * 64 + mg * 32;
    const int kv0 = half * 512;

    const unsigned short* Qb = Q + (size_t)bh * 1024 * 64;
    const unsigned short* Kb = K + (size_t)bh * 1024 * 64;
    const unsigned short* Vb = Vt + (size_t)bh * 64 * 1024;

    short8 aq[2][2];
    #pragma unroll
    for (int mm = 0; mm < 2; ++mm) {
        const unsigned short* qr = Qb + (size_t)(qrow0 + mm * 16 + lrow) * 64;
        aq[mm][0] = *(const short8*)(qr + quad * 8);
        aq[mm][1] = *(const short8*)(qr + 32 + quad * 8);
    }

    const floatx4 zero = { 0.f, 0.f, 0.f, 0.f };
    float part[2][4];
    floatx4 Oacc[2][4];
    #pragma unroll
    for (int mm = 0; mm < 2; ++mm) {
        #pragma unroll
        for (int r = 0; r < 4; ++r) part[mm][r] = 0.f;
        #pragma unroll
        for (int t = 0; t < 4; ++t) Oacc[mm][t] = zero;
    }

    for (int jt = 0; jt < 8; ++jt) {
        const int j0 = kv0 + jt * 64;
        const int buf = jt & 1;

        // K fragments: 4 n-tiles x 2 k-frags (contiguous row reads of K)
        short8 kf[4][2];
        #pragma unroll
        for (int g = 0; g < 4; ++g) {
            const unsigned short* kr = Kb + (size_t)(j0 + g * 16 + lrow) * 64;
            kf[g][0] = *(const short8*)(kr + quad * 8);
            kf[g][1] = *(const short8*)(kr + 32 + quad * 8);
        }

        // S = Q K^T for both m-tiles, 4 n-tiles
        floatx4 S[2][4];
        #pragma unroll
        for (int mm = 0; mm < 2; ++mm)
            #pragma unroll
            for (int g = 0; g < 4; ++g) {
                floatx4 s = zero;
                s = MFMA16(aq[mm][0], kf[g][0], s);
                s = MFMA16(aq[mm][1], kf[g][1], s);
                S[mm][g] = s;
            }

        // V fragments issued now, in flight during exp + LDS round-trip
        short8 vf[4][2];
        #pragma unroll
        for (int t = 0; t < 4; ++t) {
            const unsigned short* vr = Vb + (size_t)(t * 16 + lrow) * 1024 + j0;
            vf[t][0] = *(const short8*)(vr + quad * 8);
            vf[t][1] = *(const short8*)(vr + 32 + quad * 8);
        }

        // p = 2^s (log2e folded into Q); write P tile (trunc-to-bf16 stores)
        #pragma unroll
        for (int mm = 0; mm < 2; ++mm)
            #pragma unroll
            for (int g = 0; g < 4; ++g)
                #pragma unroll
                for (int r = 0; r < 4; ++r) {
                    float p = EXP2(S[mm][g][r]);
                    part[mm][r] += p;
                    ldsP[wave][buf][mm][quad * 4 + r][g * 16 + lrow] = f2bf_trunc(p);
                }

        // P: C-layout -> A-layout via wave-private LDS (no barrier needed)
        short8 aP[2][2];
        #pragma unroll
        for (int mm = 0; mm < 2; ++mm) {
            aP[mm][0] = *(const short8*)(&ldsP[wave][buf][mm][lrow][quad * 8]);
            aP[mm][1] = *(const short8*)(&ldsP[wave][buf][mm][lrow][32 + quad * 8]);
        }

        // O += P V
        #pragma unroll
        for (int t = 0; t < 4; ++t)
            #pragma unroll
            for (int mm = 0; mm < 2; ++mm) {
                Oacc[mm][t] = MFMA16(aP[mm][0], vf[t][0], Oacc[mm][t]);
                Oacc[mm][t] = MFMA16(aP[mm][1], vf[t][1], Oacc[mm][t]);
            }
    }

    // ---- combine KV halves (exact: O and sum(p) add linearly) ----
    __syncthreads();
    float* fbuf = (float*)ldsP;
    float* obuf = fbuf;          // [2 mg][32 i][64 lane]
    float* pbuf = fbuf + 4096;   // [2 mg][8 i][64 lane]
    if (half == 1) {
        #pragma unroll
        for (int mm = 0; mm < 2; ++mm) {
            #pragma unroll
            for (int t = 0; t < 4; ++t)
                #pragma unroll
                for (int r = 0; r < 4; ++r)
                    obuf[(mg * 32 + mm * 16 + t * 4 + r) * 64 + lane] = Oacc[mm][t][r];
            #pragma unroll
            for (int r = 0; r < 4; ++r)
                pbuf[(mg * 8 + mm * 4 + r) * 64 + lane] = part[mm][r];
        }
    }
    __syncthreads();
    if (half == 0) {
        #pragma unroll
        for (int mm = 0; mm < 2; ++mm) {
            float inv[4];
            #pragma unroll
            for (int r = 0; r < 4; ++r) {
                float ts = part[mm][r] + pbuf[(mg * 8 + mm * 4 + r) * 64 + lane];
                ts += __shfl_xor(ts, 1);
                ts += __shfl_xor(ts, 2);
                ts += __shfl_xor(ts, 4);
                ts += __shfl_xor(ts, 8);
                inv[r] = RCP(ts);
            }
            #pragma unroll
            for (int t = 0; t < 4; ++t)
                #pragma unroll
                for (int r = 0; r < 4; ++r) {
                    float val = (Oacc[mm][t][r]
                        + obuf[(mg * 32 + mm * 16 + t * 4 + r) * 64 + lane]) * inv[r];
                    size_t idx = ((size_t)(b * 1024 + qrow0 + mm * 16 + quad * 4 + r)) * 768
                               + h * 64 + t * 16 + lrow;
                    AO[idx] = f2bf(val);
                }
        }
    }
}

// ---------------------------------------------------------------------------
// Phase 3: Y = AO @ Wo^T + bo. AO [8192 x 768] bf16, Wob bf16, Y f32.
// grid (12, 64), block 256; wave = 32 rows (B-frags reused across 2 m-tiles).
// (M=16 / grid(12,128) variant measured ~28us slower in round 7.)
// ---------------------------------------------------------------------------
__global__ __launch_bounds__(256) void out_proj(
    const unsigned short* __restrict__ AO, const unsigned short* __restrict__ Wob,
    const float* __restrict__ bo, float* __restrict__ Y)
{
    const int wave = threadIdx.x >> 6, lane = threadIdx.x & 63;
    const int lrow = lane & 15, quad = lane >> 4;
    const int row0 = blockIdx.y * 128 + wave * 32;
    const int c0 = blockIdx.x * 64;

    const floatx4 zero = { 0.f, 0.f, 0.f, 0.f };
    floatx4 acc[2][4];
    #pragma unroll
    for (int m = 0; m < 2; ++m)
        #pragma unroll
        for (int t = 0; t < 4; ++t) acc[m][t] = zero;

    for (int k0 = 0; k0 < 768; k0 += 32) {
        short8 a[2];
        #pragma unroll
        for (int m = 0; m < 2; ++m)
            a[m] = *(const short8*)(AO + (size_t)(row0 + m * 16 + lrow) * 768
                                    + k0 + quad * 8);
        #pragma unroll
        for (int t = 0; t < 4; ++t) {
            short8 bfr = *(const short8*)(Wob + (size_t)(c0 + t * 16 + lrow) * 768
                                          + k0 + quad * 8);
            #pragma unroll
            for (int m = 0; m < 2; ++m)
                acc[m][t] = MFMA16(a[m], bfr, acc[m][t]);
        }
    }
    #pragma unroll
    for (int t = 0; t < 4; ++t) {
        float bias = bo[c0 + t * 16 + lrow];
        #pragma unroll
        for (int m = 0; m < 2; ++m)
            #pragma unroll
            for (int r = 0; r < 4; ++r) {
                Y[(size_t)(row0 + m * 16 + quad * 4 + r) * 768 + c0 + t * 16 + lrow]
                    = acc[m][t][r] + bias;
            }
    }
}

extern "C" void kernel_launch(void* const* d_in, const int* in_sizes, int n_in,
                              void* d_out, int out_size, void* d_ws, size_t ws_size,
                              hipStream_t stream)
{
    const float* x  = (const float*)d_in[0];
    const float* Wq = (const float*)d_in[1];
    const float* Wk = (const float*)d_in[2];
    const float* Wv = (const float*)d_in[3];
    const float* bq = (const float*)d_in[4];
    const float* bk = (const float*)d_in[5];
    const float* bv = (const float*)d_in[6];
    const float* Wo = (const float*)d_in[7];
    const float* bo = (const float*)d_in[8];

    // ws layout (bf16 elements)
    unsigned short* Q   = (unsigned short*)d_ws;        // 6291456
    unsigned short* K   = Q + 6291456;                  // 6291456
    unsigned short* Vt  = K + 6291456;                  // 6291456 (transposed)
    unsigned short* AO  = Vt + 6291456;                 // 6291456
    unsigned short* Wqt = AO + 6291456;                 // 49152
    unsigned short* Wkt = Wqt + 49152;                  // 49152
    unsigned short* Wvt = Wkt + 49152;                  // 49152
    unsigned short* Wob = Wvt + 49152;                  // 589824
    float* Y = (float*)d_out;

    prep_weights<<<dim3(576), 256, 0, stream>>>(Wq, Wk, Wv, Wo, Wqt, Wkt, Wvt, Wob);
    qkv_proj<<<dim3(16, 96), 256, 0, stream>>>(x, Wqt, Wkt, Wvt, bq, bk, bv, Q, K, Vt);
    attn_kernel<<<dim3(16, 96), 256, 0, stream>>>(Q, K, Vt, AO);
    out_proj<<<dim3(12, 64), 256, 0, stream>>>(AO, Wob, bo, Y);
}